// Round 8
// baseline (123.769 us; speedup 1.0000x reference)
//
#include <hip/hip_runtime.h>

// mads (type='nwd', kernel='gauss') forward: Gaussian-kernel attention.
// out[b,q,v] = sum_k softmax_k(-0.5*||K[b,k]*W - Q[b,q]*W||^2) * V[b,k,v]
//
// R8: R4-proven mono structure, but query blocks of 32 (grid 1024) instead
// of 64 (grid 512). Queries are independent -> no merge/normalize overhead
// (unlike R5/R6 split-K). Grid was the occupancy cap (2 WG/CU); now 4 WG/CU
// x 8 waves = 32 waves/CU. Per-wave state halves (2 q-subtiles), LDS 43->22KB.
// No XCD swizzle, no manual prefetch (R7 falsified both as bundled).

#define L2E 1.4426950408889634f

typedef float f32x4 __attribute__((ext_vector_type(4)));
typedef short s16x8 __attribute__((ext_vector_type(8)));

__device__ __forceinline__ unsigned int f2bf(float f) {
    unsigned int u = __float_as_uint(f);
    return (u + 0x7FFFu + ((u >> 16) & 1u)) >> 16;   // RNE f32->bf16
}
__device__ __forceinline__ float bf2f(unsigned int h) {
    return __uint_as_float(h << 16);
}
__device__ __forceinline__ float exp2_hw(float x) {
    float r;
    asm("v_exp_f32 %0, %1" : "=v"(r) : "v"(x));      // r = 2^x
    return r;
}
__device__ __forceinline__ unsigned int cvt_pk_bf16(float lo, float hi) {
    unsigned int r;
    asm("v_cvt_pk_bf16_f32 %0, %1, %2" : "=v"(r) : "v"(lo), "v"(hi));
    return r;
}

// ---------------- pre-pass: K -> khi/klo bf16 + (-0.5*k2) ----------------
__global__ __launch_bounds__(256)
void prep_k_kernel(const float* __restrict__ K, const float* __restrict__ Wp,
                   unsigned short* __restrict__ KHI, unsigned short* __restrict__ KLO,
                   float* __restrict__ K2S)
{
    const size_t gtid = (size_t)blockIdx.x * 256 + threadIdx.x;
    const int row = (int)(gtid >> 3);        // (b*4096 + n)
    const int c0  = ((int)gtid & 7) * 4;     // dk chunk
    const float4 k = *(const float4*)(K + (size_t)row * 32 + c0);
    const float4 w = *(const float4*)(Wp + c0);
    float ks0 = k.x * w.x, ks1 = k.y * w.y, ks2 = k.z * w.z, ks3 = k.w * w.w;
    float pk = ks0 * ks0 + ks1 * ks1 + ks2 * ks2 + ks3 * ks3;
    pk += __shfl_xor(pk, 1);
    pk += __shfl_xor(pk, 2);
    pk += __shfl_xor(pk, 4);
    if (c0 == 0) K2S[row] = -0.5f * pk;
    unsigned int h0 = f2bf(ks0), h1 = f2bf(ks1), h2 = f2bf(ks2), h3 = f2bf(ks3);
    unsigned int l0 = f2bf(ks0 - bf2f(h0)), l1 = f2bf(ks1 - bf2f(h1));
    unsigned int l2 = f2bf(ks2 - bf2f(h2)), l3 = f2bf(ks3 - bf2f(h3));
    uint2 hp, lp;
    hp.x = h0 | (h1 << 16); hp.y = h2 | (h3 << 16);
    lp.x = l0 | (l1 << 16); lp.y = l2 | (l3 << 16);
    *(uint2*)(KHI + (size_t)row * 32 + c0) = hp;
    *(uint2*)(KLO + (size_t)row * 32 + c0) = lp;
}

// ---------------- pre-pass: V -> V^T bf16 [b][32][4096] ----------------
__global__ __launch_bounds__(256)
void prep_v_kernel(const float* __restrict__ V, unsigned short* __restrict__ VT)
{
    __shared__ unsigned short tile[32][72];
    const int t  = threadIdx.x;
    const int b  = blockIdx.x >> 6;
    const int n0 = (blockIdx.x & 63) * 64;
    {
        const int nl = t >> 2, c0 = (t & 3) * 8;
        const float* vp = V + ((size_t)(b * 4096 + n0 + nl)) * 32 + c0;
        const float4 a = *(const float4*)vp;
        const float4 c = *(const float4*)(vp + 4);
        tile[c0 + 0][nl] = (unsigned short)f2bf(a.x);
        tile[c0 + 1][nl] = (unsigned short)f2bf(a.y);
        tile[c0 + 2][nl] = (unsigned short)f2bf(a.z);
        tile[c0 + 3][nl] = (unsigned short)f2bf(a.w);
        tile[c0 + 4][nl] = (unsigned short)f2bf(c.x);
        tile[c0 + 5][nl] = (unsigned short)f2bf(c.y);
        tile[c0 + 6][nl] = (unsigned short)f2bf(c.z);
        tile[c0 + 7][nl] = (unsigned short)f2bf(c.w);
    }
    __syncthreads();
    {
        const int v = t >> 3, ch = (t & 7) * 8;
        s16x8 o;
        #pragma unroll
        for (int j = 0; j < 8; ++j) o[j] = (short)tile[v][ch + j];
        *(s16x8*)(VT + ((size_t)(b * 32 + v)) * 4096 + n0 + ch) = o;
    }
}

// ---------------- main kernel: 512 threads = 8 waves, 32-query blocks ----------------
__global__ __launch_bounds__(512, 4)
void mads_mono_kernel(const unsigned short* __restrict__ KHI,
                      const unsigned short* __restrict__ KLO,
                      const unsigned short* __restrict__ VT,
                      const float* __restrict__ K2S,
                      const float* __restrict__ Q,
                      const float* __restrict__ Wp,
                      float* __restrict__ OUT)
{
    constexpr int N = 4096, D = 32;
    constexpr int NW = 8;          // waves per WG
    constexpr int NS = 2;          // q-subtiles per wave (32 queries)
    constexpr int KPW = N / NW;    // 512 keys per wave
    constexpr int RND = KPW / 32;  // 16 rounds of 32 keys

    __shared__ __align__(16) unsigned int pbuf[NW][NS][16][16];  // 16 KB
    __shared__ float lbuf[NW][NS][16];      // [wave][sub][q] partial l
    __shared__ float sumb[NS][32][16];      // [sub][v][q] merge accumulator

    const int tid  = threadIdx.x;
    const int lane = tid & 63;
    const int w    = tid >> 6;
    const int g    = lane >> 4;
    const int qi   = lane & 15;
    const int b    = blockIdx.x >> 7;            // batch 0..7
    const int q0   = (blockIdx.x & 127) * 32;    // query block base

    for (int i = tid; i < NS * 32 * 16; i += 512) ((float*)sumb)[i] = 0.f;

    // Q fragments (B-operand), hi/lo split + per-query shift -0.5*q2*L2E
    float w8[8];
    {
        const float* wp = Wp + g * 8;
        #pragma unroll
        for (int j = 0; j < 8; ++j) w8[j] = wp[j];
    }
    s16x8 qhi[NS], qlo[NS];
    float nq2L[NS];
    #pragma unroll
    for (int sub = 0; sub < NS; ++sub) {
        const float* qp = Q + ((size_t)(b * N + q0 + sub * 16 + qi)) * D + g * 8;
        float s = 0.f;
        #pragma unroll
        for (int j = 0; j < 8; ++j) {
            float qs = qp[j] * w8[j];
            s = fmaf(qs, qs, s);
            unsigned int h = f2bf(qs);
            qhi[sub][j] = (short)h;
            qlo[sub][j] = (short)f2bf(qs - bf2f(h));
        }
        s += __shfl_xor(s, 16);
        s += __shfl_xor(s, 32);
        nq2L[sub] = -0.5f * s * L2E;   // every lane: full q2 for column qi
    }

    f32x4 acc[NS][2];
    #pragma unroll
    for (int s = 0; s < NS; ++s)
        #pragma unroll
        for (int v = 0; v < 2; ++v)
            #pragma unroll
            for (int i = 0; i < 4; ++i) acc[s][v][i] = 0.f;

    float l_run[NS] = {0.f, 0.f};
    const int pcr = (g + (qi >> 1)) & 3;   // P read chunk (swizzle inverse)

    for (int rnd = 0; rnd < RND; ++rnd) {
        const int kb = w * KPW + rnd * 32;

        // ---- all loads for this round: vector loads from prepped ws ----
        const size_t krow = ((size_t)(b * N + kb + qi)) * 32 + g * 8;
        const s16x8 kh0 = *(const s16x8*)(KHI + krow);
        const s16x8 kh1 = *(const s16x8*)(KHI + krow + 16 * 32);
        const s16x8 kl0 = *(const s16x8*)(KLO + krow);
        const s16x8 kl1 = *(const s16x8*)(KLO + krow + 16 * 32);
        const f32x4 k2c0 = *(const f32x4*)(K2S + b * N + kb + g * 4);
        const f32x4 k2c1 = *(const f32x4*)(K2S + b * N + kb + 16 + g * 4);
        const s16x8 vf0 = *(const s16x8*)(VT + ((size_t)(b * 32 + qi)) * N + kb + g * 8);
        const s16x8 vf1 = *(const s16x8*)(VT + ((size_t)(b * 32 + 16 + qi)) * N + kb + g * 8);

        // ---- QK^T (split precision) + exp + P write ----
        #pragma unroll
        for (int sub = 0; sub < NS; ++sub) {
            f32x4 sv[2];
            sv[0] = k2c0;
            sv[1] = k2c1;
            sv[0] = __builtin_amdgcn_mfma_f32_16x16x32_bf16(kl0, qhi[sub], sv[0], 0, 0, 0);
            sv[0] = __builtin_amdgcn_mfma_f32_16x16x32_bf16(kh0, qlo[sub], sv[0], 0, 0, 0);
            sv[0] = __builtin_amdgcn_mfma_f32_16x16x32_bf16(kh0, qhi[sub], sv[0], 0, 0, 0);
            sv[1] = __builtin_amdgcn_mfma_f32_16x16x32_bf16(kl1, qhi[sub], sv[1], 0, 0, 0);
            sv[1] = __builtin_amdgcn_mfma_f32_16x16x32_bf16(kh1, qlo[sub], sv[1], 0, 0, 0);
            sv[1] = __builtin_amdgcn_mfma_f32_16x16x32_bf16(kh1, qhi[sub], sv[1], 0, 0, 0);

            // p = exp(score - 0.5*q2) = exp(-0.5*d2) in (0,1]
            float p[8];
            #pragma unroll
            for (int kst = 0; kst < 2; ++kst)
                #pragma unroll
                for (int r = 0; r < 4; ++r)
                    p[kst * 4 + r] = exp2_hw(fmaf(sv[kst][r], L2E, nq2L[sub]));

            l_run[sub] += ((p[0] + p[1]) + (p[2] + p[3]))
                        + ((p[4] + p[5]) + (p[6] + p[7]));

            unsigned int pd[2][2];
            pd[0][0] = cvt_pk_bf16(p[0], p[1]);
            pd[0][1] = cvt_pk_bf16(p[2], p[3]);
            pd[1][0] = cvt_pk_bf16(p[4], p[5]);
            pd[1][1] = cvt_pk_bf16(p[6], p[7]);
            #pragma unroll
            for (int kst = 0; kst < 2; ++kst) {
                int c  = kst * 2 + (g >> 1);
                int pc = (c + (qi >> 1)) & 3;
                unsigned long long pack64 =
                    (unsigned long long)pd[kst][0] |
                    ((unsigned long long)pd[kst][1] << 32);
                *(unsigned long long*)&pbuf[w][sub][qi][pc * 4 + (g & 1) * 2] = pack64;
            }
        }

        // ---- PV: acc[v][q] += V^T . P ----
        #pragma unroll
        for (int sub = 0; sub < NS; ++sub) {
            s16x8 pf = *(const s16x8*)&pbuf[w][sub][qi][pcr * 4];
            acc[sub][0] = __builtin_amdgcn_mfma_f32_16x16x32_bf16(vf0, pf, acc[sub][0], 0, 0, 0);
            acc[sub][1] = __builtin_amdgcn_mfma_f32_16x16x32_bf16(vf1, pf, acc[sub][1], 0, 0, 0);
        }
    }

    // ---- merge the 8 wave-partials (pure sums — no max bookkeeping) ----
    #pragma unroll
    for (int sub = 0; sub < NS; ++sub) {
        float lv = l_run[sub];
        lv += __shfl_xor(lv, 16);
        lv += __shfl_xor(lv, 32);
        if (g == 0) lbuf[w][sub][qi] = lv;
    }
    __syncthreads();

    #pragma unroll
    for (int sub = 0; sub < NS; ++sub)
        #pragma unroll
        for (int vt = 0; vt < 2; ++vt)
            #pragma unroll
            for (int r = 0; r < 4; ++r)
                atomicAdd(&sumb[sub][vt * 16 + g * 4 + r][qi], acc[sub][vt][r]);
    __syncthreads();

    // ---- store: 1024 f32 per WG (threads 0..255, 4 each); divide by total l ----
    if (tid < 256) {
        const int sub = tid >> 7;
        const int q   = (tid >> 3) & 15;
        const int v0  = (tid & 7) * 4;
        float lt = 0.f;
        #pragma unroll
        for (int ww = 0; ww < NW; ++ww) lt += lbuf[ww][sub][q];
        const float inv = 1.0f / lt;
        float* op = OUT + ((size_t)(b * N + q0 + sub * 16 + q)) * D + v0;
        #pragma unroll
        for (int i = 0; i < 4; ++i) op[i] = sumb[sub][v0 + i][q] * inv;
    }
}

// ---------------- fallback (R1-style, passed in R1) if ws too small ----------------
__global__ __launch_bounds__(256, 2)
void mads_fb_kernel(const float* __restrict__ K,
                    const float* __restrict__ V,
                    const float* __restrict__ Q,
                    const float* __restrict__ Wp,
                    float* __restrict__ OUT)
{
    constexpr int N  = 4096, D = 32;
    constexpr int NW = 4;
    constexpr int KPW = N / NW;
    constexpr int RND = KPW / 32;

    __shared__ __align__(16) unsigned int pbuf[NW][4][16][16];
    __shared__ float mlbuf[NW][4][16][2];
    __shared__ float sumb[4][32][16];

    const int tid  = threadIdx.x;
    const int lane = tid & 63;
    const int w    = tid >> 6;
    const int g    = lane >> 4;
    const int qi   = lane & 15;
    const int b    = blockIdx.x >> 6;
    const int q0   = (blockIdx.x & 63) * 64;

    for (int i = tid; i < 4 * 32 * 16; i += 256) ((float*)sumb)[i] = 0.f;

    float w8[8];
    {
        const float* wp = Wp + g * 8;
        #pragma unroll
        for (int j = 0; j < 8; ++j) w8[j] = wp[j];
    }

    s16x8 qhi[4], qlo[4];
    #pragma unroll
    for (int sub = 0; sub < 4; ++sub) {
        const float* qp = Q + ((size_t)(b * N + q0 + sub * 16 + qi)) * D + g * 8;
        #pragma unroll
        for (int j = 0; j < 8; ++j) {
            float qs = qp[j] * w8[j];
            unsigned int h = f2bf(qs);
            qhi[sub][j] = (short)h;
            qlo[sub][j] = (short)f2bf(qs - bf2f(h));
        }
    }

    f32x4 acc[4][2];
    #pragma unroll
    for (int s = 0; s < 4; ++s)
        #pragma unroll
        for (int v = 0; v < 2; ++v)
            #pragma unroll
            for (int i = 0; i < 4; ++i) acc[s][v][i] = 0.f;

    float m_run[4] = {-1e30f, -1e30f, -1e30f, -1e30f};
    float l_run[4] = {0.f, 0.f, 0.f, 0.f};

    for (int rnd = 0; rnd < RND; ++rnd) {
        const int kb = w * KPW + rnd * 32;

        float kraw[2][8], vraw[2][8];
        #pragma unroll
        for (int kst = 0; kst < 2; ++kst) {
            const float* kp = K + ((size_t)(b * N + kb + kst * 16 + qi)) * D + g * 8;
            #pragma unroll
            for (int j = 0; j < 8; ++j) kraw[kst][j] = kp[j];
        }
        #pragma unroll
        for (int vt = 0; vt < 2; ++vt) {
            const float* vp = V + ((size_t)(b * N + kb + g * 8)) * D + vt * 16 + qi;
            #pragma unroll
            for (int j = 0; j < 8; ++j) vraw[vt][j] = vp[(size_t)j * D];
        }

        s16x8 khi[2], klo[2];
        f32x4 k2c[2];
        #pragma unroll
        for (int kst = 0; kst < 2; ++kst) {
            float pk = 0.f;
            #pragma unroll
            for (int j = 0; j < 8; ++j) {
                float ks = kraw[kst][j] * w8[j];
                pk = fmaf(ks, ks, pk);
                unsigned int h = f2bf(ks);
                khi[kst][j] = (short)h;
                klo[kst][j] = (short)f2bf(ks - bf2f(h));
            }
            pk += __shfl_xor(pk, 16);
            pk += __shfl_xor(pk, 32);
            pk *= -0.5f;
            #pragma unroll
            for (int r = 0; r < 4; ++r)
                k2c[kst][r] = __shfl(pk, ((lane >> 4) << 2) + r);
        }

        #pragma unroll
        for (int sub = 0; sub < 4; ++sub) {
            f32x4 sv[2];
            sv[0] = k2c[0];
            sv[1] = k2c[1];
            sv[0] = __builtin_amdgcn_mfma_f32_16x16x32_bf16(klo[0], qhi[sub], sv[0], 0, 0, 0);
            sv[0] = __builtin_amdgcn_mfma_f32_16x16x32_bf16(khi[0], qlo[sub], sv[0], 0, 0, 0);
            sv[0] = __builtin_amdgcn_mfma_f32_16x16x32_bf16(khi[0], qhi[sub], sv[0], 0, 0, 0);
            sv[1] = __builtin_amdgcn_mfma_f32_16x16x32_bf16(klo[1], qhi[sub], sv[1], 0, 0, 0);
            sv[1] = __builtin_amdgcn_mfma_f32_16x16x32_bf16(khi[1], qlo[sub], sv[1], 0, 0, 0);
            sv[1] = __builtin_amdgcn_mfma_f32_16x16x32_bf16(khi[1], qhi[sub], sv[1], 0, 0, 0);

            float tm = sv[0][0];
            tm = fmaxf(tm, sv[0][1]); tm = fmaxf(tm, sv[0][2]); tm = fmaxf(tm, sv[0][3]);
            tm = fmaxf(tm, sv[1][0]); tm = fmaxf(tm, sv[1][1]);
            tm = fmaxf(tm, sv[1][2]); tm = fmaxf(tm, sv[1][3]);
            tm = fmaxf(tm, __shfl_xor(tm, 16));
            tm = fmaxf(tm, __shfl_xor(tm, 32));

            float mnew  = fmaxf(m_run[sub], tm);
            float scale = exp2_hw((m_run[sub] - mnew) * L2E);
            m_run[sub]  = mnew;
            float nmL   = -mnew * L2E;

            acc[sub][0] *= scale;
            acc[sub][1] *= scale;

            float ps = 0.f;
            unsigned int pd[2][2];
            #pragma unroll
            for (int kst = 0; kst < 2; ++kst) {
                float p[4];
                #pragma unroll
                for (int r = 0; r < 4; ++r) {
                    p[r] = exp2_hw(fmaf(sv[kst][r], L2E, nmL));
                    ps += p[r];
                }
                pd[kst][0] = f2bf(p[0]) | (f2bf(p[1]) << 16);
                pd[kst][1] = f2bf(p[2]) | (f2bf(p[3]) << 16);
            }
            l_run[sub] = l_run[sub] * scale + ps;

            #pragma unroll
            for (int kst = 0; kst < 2; ++kst) {
                int c  = kst * 2 + (g >> 1);
                int pc = (c + (qi >> 1)) & 3;
                unsigned long long pack64 =
                    (unsigned long long)pd[kst][0] |
                    ((unsigned long long)pd[kst][1] << 32);
                *(unsigned long long*)&pbuf[w][sub][qi][pc * 4 + (g & 1) * 2] = pack64;
            }
        }

        s16x8 vfr[2];
        #pragma unroll
        for (int vt = 0; vt < 2; ++vt)
            #pragma unroll
            for (int j = 0; j < 8; ++j) vfr[vt][j] = (short)f2bf(vraw[vt][j]);

        const int pcr = (g + (qi >> 1)) & 3;
        #pragma unroll
        for (int sub = 0; sub < 4; ++sub) {
            s16x8 pf = *(const s16x8*)&pbuf[w][sub][qi][pcr * 4];
            acc[sub][0] = __builtin_amdgcn_mfma_f32_16x16x32_bf16(vfr[0], pf, acc[sub][0], 0, 0, 0);
            acc[sub][1] = __builtin_amdgcn_mfma_f32_16x16x32_bf16(vfr[1], pf, acc[sub][1], 0, 0, 0);
        }
    }

    #pragma unroll
    for (int sub = 0; sub < 4; ++sub) {
        float lv = l_run[sub];
        lv += __shfl_xor(lv, 16);
        lv += __shfl_xor(lv, 32);
        l_run[sub] = lv;
    }
    if (g == 0) {
        #pragma unroll
        for (int sub = 0; sub < 4; ++sub) {
            mlbuf[w][sub][qi][0] = m_run[sub];
            mlbuf[w][sub][qi][1] = l_run[sub];
        }
    }
    __syncthreads();

    #pragma unroll
    for (int sub = 0; sub < 4; ++sub) {
        float M = -1e30f;
        float mv[NW], lv[NW];
        #pragma unroll
        for (int ww = 0; ww < NW; ++ww) {
            mv[ww] = mlbuf[ww][sub][qi][0];
            lv[ww] = mlbuf[ww][sub][qi][1];
            M = fmaxf(M, mv[ww]);
        }
        float denom = 0.f;
        #pragma unroll
        for (int ww = 0; ww < NW; ++ww)
            denom += lv[ww] * exp2_hw((mv[ww] - M) * L2E);
        float sc = exp2_hw((m_run[sub] - M) * L2E) / denom;
        #pragma unroll
        for (int vt = 0; vt < 2; ++vt)
            #pragma unroll
            for (int r = 0; r < 4; ++r)
                atomicAdd(&sumb[sub][vt * 16 + g * 4 + r][qi], acc[sub][vt][r] * sc);
    }
    __syncthreads();

    {
        const int sub = tid >> 6;
        const int q   = (tid >> 2) & 15;
        const int v0  = (tid & 3) * 8;
        float* op = OUT + ((size_t)(b * N + q0 + sub * 16 + q)) * D + v0;
        #pragma unroll
        for (int i = 0; i < 8; ++i) op[i] = sumb[sub][v0 + i][q];
    }
}

extern "C" void kernel_launch(void* const* d_in, const int* in_sizes, int n_in,
                              void* d_out, int out_size, void* d_ws, size_t ws_size,
                              hipStream_t stream) {
    const float* K  = (const float*)d_in[0];
    const float* V  = (const float*)d_in[1];
    const float* Q  = (const float*)d_in[2];
    const float* W  = (const float*)d_in[3];
    float* OUT = (float*)d_out;
    (void)in_sizes; (void)n_in; (void)out_size;

    constexpr size_t NEL = (size_t)8 * 4096 * 32;
    constexpr size_t NROW = (size_t)8 * 4096;
    constexpr size_t NEED_MONO = NEL * 2 * 3 + NROW * 4;

    if (ws_size >= NEED_MONO) {
        unsigned short* khi = (unsigned short*)d_ws;
        unsigned short* klo = khi + NEL;
        unsigned short* vt  = klo + NEL;
        float*          k2s = (float*)(vt + NEL);
        hipLaunchKernelGGL(prep_k_kernel, dim3(1024), dim3(256), 0, stream, K, W, khi, klo, k2s);
        hipLaunchKernelGGL(prep_v_kernel, dim3(512),  dim3(256), 0, stream, V, vt);
        hipLaunchKernelGGL(mads_mono_kernel, dim3(1024), dim3(512), 0, stream,
                           khi, klo, vt, k2s, Q, W, OUT);
    } else {
        hipLaunchKernelGGL(mads_fb_kernel, dim3(512), dim3(256), 0, stream,
                           K, V, Q, W, OUT);
    }
}

// Round 9
// 95.695 us; speedup vs baseline: 1.2934x; 1.2934x over previous
//
#include <hip/hip_runtime.h>

// mads (type='nwd', kernel='gauss') forward: Gaussian-kernel attention.
// out[b,q,v] = sum_k softmax_k(-0.5*||K[b,k]*W - Q[b,q]*W||^2) * V[b,k,v]
//
// R9: EXACT R4 structure (grid 512, 64-query blocks, 8 waves, fixed-shift
// softmax, pbuf PV path — 97.8us proven) + ONE change: XCD-locality swizzle
// b = bid&7 (bid%8 -> XCD), q0 = (bid>>3)*64. Each XCD then caches exactly
// one batch's working set (~1.3MB << 4MB L2) instead of thrashing on all
// 8 batches (11MB). R7 showed FETCH 30->15MB with this swizzle but bundled
// a regressive manual-prefetch rewrite; this round isolates the swizzle.

#define L2E 1.4426950408889634f

typedef float f32x4 __attribute__((ext_vector_type(4)));
typedef short s16x8 __attribute__((ext_vector_type(8)));

__device__ __forceinline__ unsigned int f2bf(float f) {
    unsigned int u = __float_as_uint(f);
    return (u + 0x7FFFu + ((u >> 16) & 1u)) >> 16;   // RNE f32->bf16
}
__device__ __forceinline__ float bf2f(unsigned int h) {
    return __uint_as_float(h << 16);
}
__device__ __forceinline__ float exp2_hw(float x) {
    float r;
    asm("v_exp_f32 %0, %1" : "=v"(r) : "v"(x));      // r = 2^x
    return r;
}
__device__ __forceinline__ unsigned int cvt_pk_bf16(float lo, float hi) {
    unsigned int r;
    asm("v_cvt_pk_bf16_f32 %0, %1, %2" : "=v"(r) : "v"(lo), "v"(hi));
    return r;
}

// ---------------- pre-pass: K -> khi/klo bf16 + (-0.5*k2) ----------------
__global__ __launch_bounds__(256)
void prep_k_kernel(const float* __restrict__ K, const float* __restrict__ Wp,
                   unsigned short* __restrict__ KHI, unsigned short* __restrict__ KLO,
                   float* __restrict__ K2S)
{
    const size_t gtid = (size_t)blockIdx.x * 256 + threadIdx.x;
    const int row = (int)(gtid >> 3);        // (b*4096 + n)
    const int c0  = ((int)gtid & 7) * 4;     // dk chunk
    const float4 k = *(const float4*)(K + (size_t)row * 32 + c0);
    const float4 w = *(const float4*)(Wp + c0);
    float ks0 = k.x * w.x, ks1 = k.y * w.y, ks2 = k.z * w.z, ks3 = k.w * w.w;
    float pk = ks0 * ks0 + ks1 * ks1 + ks2 * ks2 + ks3 * ks3;
    pk += __shfl_xor(pk, 1);
    pk += __shfl_xor(pk, 2);
    pk += __shfl_xor(pk, 4);
    if (c0 == 0) K2S[row] = -0.5f * pk;
    unsigned int h0 = f2bf(ks0), h1 = f2bf(ks1), h2 = f2bf(ks2), h3 = f2bf(ks3);
    unsigned int l0 = f2bf(ks0 - bf2f(h0)), l1 = f2bf(ks1 - bf2f(h1));
    unsigned int l2 = f2bf(ks2 - bf2f(h2)), l3 = f2bf(ks3 - bf2f(h3));
    uint2 hp, lp;
    hp.x = h0 | (h1 << 16); hp.y = h2 | (h3 << 16);
    lp.x = l0 | (l1 << 16); lp.y = l2 | (l3 << 16);
    *(uint2*)(KHI + (size_t)row * 32 + c0) = hp;
    *(uint2*)(KLO + (size_t)row * 32 + c0) = lp;
}

// ---------------- pre-pass: V -> V^T bf16 [b][32][4096] ----------------
__global__ __launch_bounds__(256)
void prep_v_kernel(const float* __restrict__ V, unsigned short* __restrict__ VT)
{
    __shared__ unsigned short tile[32][72];
    const int t  = threadIdx.x;
    const int b  = blockIdx.x >> 6;
    const int n0 = (blockIdx.x & 63) * 64;
    {
        const int nl = t >> 2, c0 = (t & 3) * 8;
        const float* vp = V + ((size_t)(b * 4096 + n0 + nl)) * 32 + c0;
        const float4 a = *(const float4*)vp;
        const float4 c = *(const float4*)(vp + 4);
        tile[c0 + 0][nl] = (unsigned short)f2bf(a.x);
        tile[c0 + 1][nl] = (unsigned short)f2bf(a.y);
        tile[c0 + 2][nl] = (unsigned short)f2bf(a.z);
        tile[c0 + 3][nl] = (unsigned short)f2bf(a.w);
        tile[c0 + 4][nl] = (unsigned short)f2bf(c.x);
        tile[c0 + 5][nl] = (unsigned short)f2bf(c.y);
        tile[c0 + 6][nl] = (unsigned short)f2bf(c.z);
        tile[c0 + 7][nl] = (unsigned short)f2bf(c.w);
    }
    __syncthreads();
    {
        const int v = t >> 3, ch = (t & 7) * 8;
        s16x8 o;
        #pragma unroll
        for (int j = 0; j < 8; ++j) o[j] = (short)tile[v][ch + j];
        *(s16x8*)(VT + ((size_t)(b * 32 + v)) * 4096 + n0 + ch) = o;
    }
}

// ---------------- main kernel: 512 threads = 8 waves ----------------
__global__ __launch_bounds__(512, 4)
void mads_main_kernel(const unsigned short* __restrict__ KHI,
                      const unsigned short* __restrict__ KLO,
                      const unsigned short* __restrict__ VT,
                      const float* __restrict__ K2S,
                      const float* __restrict__ Q,
                      const float* __restrict__ Wp,
                      float* __restrict__ OUT)
{
    constexpr int N = 4096, D = 32;
    constexpr int NW = 8;          // waves per WG
    constexpr int KPW = N / NW;    // 512 keys per wave
    constexpr int RND = KPW / 32;  // 16 rounds of 32 keys

    __shared__ __align__(16) unsigned int pbuf[NW][4][16][16];
    __shared__ float lbuf[NW][4][16];       // [wave][sub][q] partial l
    __shared__ float sumb[4][32][16];       // [sub][v][q] merge accumulator

    const int tid  = threadIdx.x;
    const int lane = tid & 63;
    const int w    = tid >> 6;
    const int g    = lane >> 4;
    const int qi   = lane & 15;
    // XCD-locality swizzle: bid%8 -> XCD, so batch b owns XCD b entirely;
    // per-XCD L2 working set = one batch (~1.3MB) instead of all 8 (11MB).
    const int b    = blockIdx.x & 7;
    const int q0   = (blockIdx.x >> 3) * 64;

    for (int i = tid; i < 4 * 32 * 16; i += 512) ((float*)sumb)[i] = 0.f;

    // Q fragments (B-operand), hi/lo split + per-query shift -0.5*q2*L2E
    float w8[8];
    {
        const float* wp = Wp + g * 8;
        #pragma unroll
        for (int j = 0; j < 8; ++j) w8[j] = wp[j];
    }
    s16x8 qhi[4], qlo[4];
    float nq2L[4];
    #pragma unroll
    for (int sub = 0; sub < 4; ++sub) {
        const float* qp = Q + ((size_t)(b * N + q0 + sub * 16 + qi)) * D + g * 8;
        float s = 0.f;
        #pragma unroll
        for (int j = 0; j < 8; ++j) {
            float qs = qp[j] * w8[j];
            s = fmaf(qs, qs, s);
            unsigned int h = f2bf(qs);
            qhi[sub][j] = (short)h;
            qlo[sub][j] = (short)f2bf(qs - bf2f(h));
        }
        s += __shfl_xor(s, 16);
        s += __shfl_xor(s, 32);
        nq2L[sub] = -0.5f * s * L2E;   // every lane: full q2 for column qi
    }

    f32x4 acc[4][2];
    #pragma unroll
    for (int s = 0; s < 4; ++s)
        #pragma unroll
        for (int v = 0; v < 2; ++v)
            #pragma unroll
            for (int i = 0; i < 4; ++i) acc[s][v][i] = 0.f;

    float l_run[4] = {0.f, 0.f, 0.f, 0.f};

    const int pcr = (g + (qi >> 1)) & 3;   // P read chunk (swizzle inverse)

    for (int rnd = 0; rnd < RND; ++rnd) {
        const int kb = w * KPW + rnd * 32;

        // ---- all loads for this round: vector loads from prepped ws ----
        const size_t krow = ((size_t)(b * N + kb + qi)) * 32 + g * 8;
        const s16x8 kh0 = *(const s16x8*)(KHI + krow);
        const s16x8 kh1 = *(const s16x8*)(KHI + krow + 16 * 32);
        const s16x8 kl0 = *(const s16x8*)(KLO + krow);
        const s16x8 kl1 = *(const s16x8*)(KLO + krow + 16 * 32);
        const f32x4 k2c0 = *(const f32x4*)(K2S + b * N + kb + g * 4);
        const f32x4 k2c1 = *(const f32x4*)(K2S + b * N + kb + 16 + g * 4);
        const s16x8 vf0 = *(const s16x8*)(VT + ((size_t)(b * 32 + qi)) * N + kb + g * 8);
        const s16x8 vf1 = *(const s16x8*)(VT + ((size_t)(b * 32 + 16 + qi)) * N + kb + g * 8);

        // ---- QK^T (split precision) + exp + P write ----
        #pragma unroll
        for (int sub = 0; sub < 4; ++sub) {
            f32x4 sv[2];
            sv[0] = k2c0;
            sv[1] = k2c1;
            sv[0] = __builtin_amdgcn_mfma_f32_16x16x32_bf16(kl0, qhi[sub], sv[0], 0, 0, 0);
            sv[0] = __builtin_amdgcn_mfma_f32_16x16x32_bf16(kh0, qlo[sub], sv[0], 0, 0, 0);
            sv[0] = __builtin_amdgcn_mfma_f32_16x16x32_bf16(kh0, qhi[sub], sv[0], 0, 0, 0);
            sv[1] = __builtin_amdgcn_mfma_f32_16x16x32_bf16(kl1, qhi[sub], sv[1], 0, 0, 0);
            sv[1] = __builtin_amdgcn_mfma_f32_16x16x32_bf16(kh1, qlo[sub], sv[1], 0, 0, 0);
            sv[1] = __builtin_amdgcn_mfma_f32_16x16x32_bf16(kh1, qhi[sub], sv[1], 0, 0, 0);

            // p = exp(score - 0.5*q2) = exp(-0.5*d2) in (0,1]
            float p[8];
            #pragma unroll
            for (int kst = 0; kst < 2; ++kst)
                #pragma unroll
                for (int r = 0; r < 4; ++r)
                    p[kst * 4 + r] = exp2_hw(fmaf(sv[kst][r], L2E, nq2L[sub]));

            l_run[sub] += ((p[0] + p[1]) + (p[2] + p[3]))
                        + ((p[4] + p[5]) + (p[6] + p[7]));

            unsigned int pd[2][2];
            pd[0][0] = cvt_pk_bf16(p[0], p[1]);
            pd[0][1] = cvt_pk_bf16(p[2], p[3]);
            pd[1][0] = cvt_pk_bf16(p[4], p[5]);
            pd[1][1] = cvt_pk_bf16(p[6], p[7]);
            #pragma unroll
            for (int kst = 0; kst < 2; ++kst) {
                int c  = kst * 2 + (g >> 1);
                int pc = (c + (qi >> 1)) & 3;
                unsigned long long pack64 =
                    (unsigned long long)pd[kst][0] |
                    ((unsigned long long)pd[kst][1] << 32);
                *(unsigned long long*)&pbuf[w][sub][qi][pc * 4 + (g & 1) * 2] = pack64;
            }
        }

        // ---- PV: acc[v][q] += V^T . P ----
        #pragma unroll
        for (int sub = 0; sub < 4; ++sub) {
            s16x8 pf = *(const s16x8*)&pbuf[w][sub][qi][pcr * 4];
            acc[sub][0] = __builtin_amdgcn_mfma_f32_16x16x32_bf16(vf0, pf, acc[sub][0], 0, 0, 0);
            acc[sub][1] = __builtin_amdgcn_mfma_f32_16x16x32_bf16(vf1, pf, acc[sub][1], 0, 0, 0);
        }
    }

    // ---- merge the 8 wave-partials (pure sums — no max bookkeeping) ----
    #pragma unroll
    for (int sub = 0; sub < 4; ++sub) {
        float lv = l_run[sub];
        lv += __shfl_xor(lv, 16);
        lv += __shfl_xor(lv, 32);
        if (g == 0) lbuf[w][sub][qi] = lv;
    }
    __syncthreads();

    #pragma unroll
    for (int sub = 0; sub < 4; ++sub)
        #pragma unroll
        for (int vt = 0; vt < 2; ++vt)
            #pragma unroll
            for (int r = 0; r < 4; ++r)
                atomicAdd(&sumb[sub][vt * 16 + g * 4 + r][qi], acc[sub][vt][r]);
    __syncthreads();

    // ---- store: 2048 f32 per WG, 4 per thread; divide by total l ----
    {
        const int sub = tid >> 7;
        const int q   = (tid >> 3) & 15;
        const int v0  = (tid & 7) * 4;
        float lt = 0.f;
        #pragma unroll
        for (int ww = 0; ww < NW; ++ww) lt += lbuf[ww][sub][q];
        const float inv = 1.0f / lt;
        float* op = OUT + ((size_t)(b * N + q0 + sub * 16 + q)) * D + v0;
        #pragma unroll
        for (int i = 0; i < 4; ++i) op[i] = sumb[sub][v0 + i][q] * inv;
    }
}

// ---------------- fallback (R1-style, passed in R1) if ws too small ----------------
__global__ __launch_bounds__(256, 2)
void mads_fb_kernel(const float* __restrict__ K,
                    const float* __restrict__ V,
                    const float* __restrict__ Q,
                    const float* __restrict__ Wp,
                    float* __restrict__ OUT)
{
    constexpr int N  = 4096, D = 32;
    constexpr int NW = 4;
    constexpr int KPW = N / NW;
    constexpr int RND = KPW / 32;

    __shared__ __align__(16) unsigned int pbuf[NW][4][16][16];
    __shared__ float mlbuf[NW][4][16][2];
    __shared__ float sumb[4][32][16];

    const int tid  = threadIdx.x;
    const int lane = tid & 63;
    const int w    = tid >> 6;
    const int g    = lane >> 4;
    const int qi   = lane & 15;
    const int b    = blockIdx.x >> 6;
    const int q0   = (blockIdx.x & 63) * 64;

    for (int i = tid; i < 4 * 32 * 16; i += 256) ((float*)sumb)[i] = 0.f;

    float w8[8];
    {
        const float* wp = Wp + g * 8;
        #pragma unroll
        for (int j = 0; j < 8; ++j) w8[j] = wp[j];
    }

    s16x8 qhi[4], qlo[4];
    #pragma unroll
    for (int sub = 0; sub < 4; ++sub) {
        const float* qp = Q + ((size_t)(b * N + q0 + sub * 16 + qi)) * D + g * 8;
        #pragma unroll
        for (int j = 0; j < 8; ++j) {
            float qs = qp[j] * w8[j];
            unsigned int h = f2bf(qs);
            qhi[sub][j] = (short)h;
            qlo[sub][j] = (short)f2bf(qs - bf2f(h));
        }
    }

    f32x4 acc[4][2];
    #pragma unroll
    for (int s = 0; s < 4; ++s)
        #pragma unroll
        for (int v = 0; v < 2; ++v)
            #pragma unroll
            for (int i = 0; i < 4; ++i) acc[s][v][i] = 0.f;

    float m_run[4] = {-1e30f, -1e30f, -1e30f, -1e30f};
    float l_run[4] = {0.f, 0.f, 0.f, 0.f};

    for (int rnd = 0; rnd < RND; ++rnd) {
        const int kb = w * KPW + rnd * 32;

        float kraw[2][8], vraw[2][8];
        #pragma unroll
        for (int kst = 0; kst < 2; ++kst) {
            const float* kp = K + ((size_t)(b * N + kb + kst * 16 + qi)) * D + g * 8;
            #pragma unroll
            for (int j = 0; j < 8; ++j) kraw[kst][j] = kp[j];
        }
        #pragma unroll
        for (int vt = 0; vt < 2; ++vt) {
            const float* vp = V + ((size_t)(b * N + kb + g * 8)) * D + vt * 16 + qi;
            #pragma unroll
            for (int j = 0; j < 8; ++j) vraw[vt][j] = vp[(size_t)j * D];
        }

        s16x8 khi[2], klo[2];
        f32x4 k2c[2];
        #pragma unroll
        for (int kst = 0; kst < 2; ++kst) {
            float pk = 0.f;
            #pragma unroll
            for (int j = 0; j < 8; ++j) {
                float ks = kraw[kst][j] * w8[j];
                pk = fmaf(ks, ks, pk);
                unsigned int h = f2bf(ks);
                khi[kst][j] = (short)h;
                klo[kst][j] = (short)f2bf(ks - bf2f(h));
            }
            pk += __shfl_xor(pk, 16);
            pk += __shfl_xor(pk, 32);
            pk *= -0.5f;
            #pragma unroll
            for (int r = 0; r < 4; ++r)
                k2c[kst][r] = __shfl(pk, ((lane >> 4) << 2) + r);
        }

        #pragma unroll
        for (int sub = 0; sub < 4; ++sub) {
            f32x4 sv[2];
            sv[0] = k2c[0];
            sv[1] = k2c[1];
            sv[0] = __builtin_amdgcn_mfma_f32_16x16x32_bf16(klo[0], qhi[sub], sv[0], 0, 0, 0);
            sv[0] = __builtin_amdgcn_mfma_f32_16x16x32_bf16(khi[0], qlo[sub], sv[0], 0, 0, 0);
            sv[0] = __builtin_amdgcn_mfma_f32_16x16x32_bf16(khi[0], qhi[sub], sv[0], 0, 0, 0);
            sv[1] = __builtin_amdgcn_mfma_f32_16x16x32_bf16(klo[1], qhi[sub], sv[1], 0, 0, 0);
            sv[1] = __builtin_amdgcn_mfma_f32_16x16x32_bf16(khi[1], qlo[sub], sv[1], 0, 0, 0);
            sv[1] = __builtin_amdgcn_mfma_f32_16x16x32_bf16(khi[1], qhi[sub], sv[1], 0, 0, 0);

            float tm = sv[0][0];
            tm = fmaxf(tm, sv[0][1]); tm = fmaxf(tm, sv[0][2]); tm = fmaxf(tm, sv[0][3]);
            tm = fmaxf(tm, sv[1][0]); tm = fmaxf(tm, sv[1][1]);
            tm = fmaxf(tm, sv[1][2]); tm = fmaxf(tm, sv[1][3]);
            tm = fmaxf(tm, __shfl_xor(tm, 16));
            tm = fmaxf(tm, __shfl_xor(tm, 32));

            float mnew  = fmaxf(m_run[sub], tm);
            float scale = exp2_hw((m_run[sub] - mnew) * L2E);
            m_run[sub]  = mnew;
            float nmL   = -mnew * L2E;

            acc[sub][0] *= scale;
            acc[sub][1] *= scale;

            float ps = 0.f;
            unsigned int pd[2][2];
            #pragma unroll
            for (int kst = 0; kst < 2; ++kst) {
                float p[4];
                #pragma unroll
                for (int r = 0; r < 4; ++r) {
                    p[r] = exp2_hw(fmaf(sv[kst][r], L2E, nmL));
                    ps += p[r];
                }
                pd[kst][0] = f2bf(p[0]) | (f2bf(p[1]) << 16);
                pd[kst][1] = f2bf(p[2]) | (f2bf(p[3]) << 16);
            }
            l_run[sub] = l_run[sub] * scale + ps;

            #pragma unroll
            for (int kst = 0; kst < 2; ++kst) {
                int c  = kst * 2 + (g >> 1);
                int pc = (c + (qi >> 1)) & 3;
                unsigned long long pack64 =
                    (unsigned long long)pd[kst][0] |
                    ((unsigned long long)pd[kst][1] << 32);
                *(unsigned long long*)&pbuf[w][sub][qi][pc * 4 + (g & 1) * 2] = pack64;
            }
        }

        s16x8 vfr[2];
        #pragma unroll
        for (int vt = 0; vt < 2; ++vt)
            #pragma unroll
            for (int j = 0; j < 8; ++j) vfr[vt][j] = (short)f2bf(vraw[vt][j]);

        const int pcr = (g + (qi >> 1)) & 3;
        #pragma unroll
        for (int sub = 0; sub < 4; ++sub) {
            s16x8 pf = *(const s16x8*)&pbuf[w][sub][qi][pcr * 4];
            acc[sub][0] = __builtin_amdgcn_mfma_f32_16x16x32_bf16(vfr[0], pf, acc[sub][0], 0, 0, 0);
            acc[sub][1] = __builtin_amdgcn_mfma_f32_16x16x32_bf16(vfr[1], pf, acc[sub][1], 0, 0, 0);
        }
    }

    #pragma unroll
    for (int sub = 0; sub < 4; ++sub) {
        float lv = l_run[sub];
        lv += __shfl_xor(lv, 16);
        lv += __shfl_xor(lv, 32);
        l_run[sub] = lv;
    }
    if (g == 0) {
        #pragma unroll
        for (int sub = 0; sub < 4; ++sub) {
            mlbuf[w][sub][qi][0] = m_run[sub];
            mlbuf[w][sub][qi][1] = l_run[sub];
        }
    }
    __syncthreads();

    #pragma unroll
    for (int sub = 0; sub < 4; ++sub) {
        float M = -1e30f;
        float mv[NW], lv[NW];
        #pragma unroll
        for (int ww = 0; ww < NW; ++ww) {
            mv[ww] = mlbuf[ww][sub][qi][0];
            lv[ww] = mlbuf[ww][sub][qi][1];
            M = fmaxf(M, mv[ww]);
        }
        float denom = 0.f;
        #pragma unroll
        for (int ww = 0; ww < NW; ++ww)
            denom += lv[ww] * exp2_hw((mv[ww] - M) * L2E);
        float sc = exp2_hw((m_run[sub] - M) * L2E) / denom;
        #pragma unroll
        for (int vt = 0; vt < 2; ++vt)
            #pragma unroll
            for (int r = 0; r < 4; ++r)
                atomicAdd(&sumb[sub][vt * 16 + g * 4 + r][qi], acc[sub][vt][r] * sc);
    }
    __syncthreads();

    {
        const int sub = tid >> 6;
        const int q   = (tid >> 2) & 15;
        const int v0  = (tid & 3) * 8;
        float* op = OUT + ((size_t)(b * N + q0 + sub * 16 + q)) * D + v0;
        #pragma unroll
        for (int i = 0; i < 8; ++i) op[i] = sumb[sub][v0 + i][q];
    }
}

extern "C" void kernel_launch(void* const* d_in, const int* in_sizes, int n_in,
                              void* d_out, int out_size, void* d_ws, size_t ws_size,
                              hipStream_t stream) {
    const float* K  = (const float*)d_in[0];
    const float* V  = (const float*)d_in[1];
    const float* Q  = (const float*)d_in[2];
    const float* W  = (const float*)d_in[3];
    float* OUT = (float*)d_out;
    (void)in_sizes; (void)n_in; (void)out_size;

    constexpr size_t NEL = (size_t)8 * 4096 * 32;
    constexpr size_t NROW = (size_t)8 * 4096;
    constexpr size_t NEED_MONO = NEL * 2 * 3 + NROW * 4;

    if (ws_size >= NEED_MONO) {
        unsigned short* khi = (unsigned short*)d_ws;
        unsigned short* klo = khi + NEL;
        unsigned short* vt  = klo + NEL;
        float*          k2s = (float*)(vt + NEL);
        hipLaunchKernelGGL(prep_k_kernel, dim3(1024), dim3(256), 0, stream, K, W, khi, klo, k2s);
        hipLaunchKernelGGL(prep_v_kernel, dim3(512),  dim3(256), 0, stream, V, vt);
        hipLaunchKernelGGL(mads_main_kernel, dim3(512), dim3(512), 0, stream,
                           khi, klo, vt, k2s, Q, W, OUT);
    } else {
        hipLaunchKernelGGL(mads_fb_kernel, dim3(512), dim3(256), 0, stream,
                           K, V, Q, W, OUT);
    }
}